// Round 14
// baseline (262.142 us; speedup 1.0000x reference)
//
#include <hip/hip_runtime.h>
#include <hip/hip_bf16.h>
#include <math.h>

#define B_SZ 1024
#define NMAX 21
#define NN 441            // 21*21
#define HNF 256
#define TOT_ROWS (B_SZ * NN)   // 451584
#define TILES_PB 14            // 14 tiles of 32 rows per batch (448 >= 441)
#define TROWS 32
#define TPB 7                  // tiles per block (pipeline depth)

typedef short short8 __attribute__((ext_vector_type(8)));
typedef float float4v __attribute__((ext_vector_type(4)));

__device__ __forceinline__ unsigned short f2bf(float x) {
    union { float f; unsigned int u; } v; v.f = x;
    unsigned int r = v.u + 0x7FFFu + ((v.u >> 16) & 1u);   // RNE
    return (unsigned short)(r >> 16);
}

// hardware packed fp32->bf16 (v_cvt_pk_bf16_f32), RNE
__device__ __forceinline__ unsigned pk_bf16(float lo, float hi) {
    __hip_bfloat162 h = __float22bfloat162_rn(float2{lo, hi});
    return *reinterpret_cast<unsigned*>(&h);
}

// fast softplus: max(x,0) + ln2*log2(1 + exp2(-|x|*log2e)), raw v_exp/v_log
__device__ __forceinline__ float softplus_fast(float x) {
    float e = __builtin_amdgcn_exp2f(-fabsf(x) * 1.44269504088896f);
    float lg = __builtin_amdgcn_logf(1.f + e);
    return fmaxf(x, 0.f) + 0.69314718055995f * lg;
}

// fast tanh for x>=0: 1 - 2/(exp2(x*2log2e)+1). v_exp/v_rcp approx (~1e-7).
__device__ __forceinline__ float tanh_fast(float x) {
    float e = __builtin_amdgcn_exp2f(x * 2.8853900817779268f);
    float q = __builtin_amdgcn_rcpf(e + 1.f);
    return fmaf(-2.f, q, 1.f);
}

// ---------------------------------------------------------------------------
// Pack W1 into MFMA B-fragment order as bf16 (+ zero emb, folded in).
// ---------------------------------------------------------------------------
__global__ __launch_bounds__(256) void pack_w1(const float* __restrict__ W1,
                                               short* __restrict__ B0p,
                                               float* __restrict__ emb)
{
    int id = blockIdx.x * 256 + threadIdx.x;   // 0..65535
    int j = id & 7, l = (id >> 3) & 63, f = (id >> 9) & 15, s = id >> 13;
    int k = s * 32 + ((l >> 4) << 3) + j;
    int c = (f << 4) + (l & 15);
    B0p[id] = (short)f2bf(W1[k * HNF + c]);
    #pragma unroll
    for (int e = 0; e < 4; e++)
        emb[(size_t)e * 65536 + id] = 0.f;     // 4*65536 = 1024*256
}

// ---------------------------------------------------------------------------
// Kernel 1 (R14): R13 tile (32x256, 256 thr, 4 waves, 2m x 4n) + DEEP DMA
// PIPELINE. 2048 blocks; block b owns batch b/2, tiles (b&1)*7 + p, p=0..6.
// Two 32KB stage buffers ping-pong; tile p+2's global_load_lds DMA is issued
// right after tile p's epilogue barrier (in-flight state lives in the DMA
// queue, zero VGPR cost), so HBM transfer overlaps the NEXT tile's full
// convert+MFMA+epilogue. Wave-local vmcnt(8) = "tile p landed, tile p+1
// still flying". Convert/swizzle/MFMA/epilogue identical to R13. emb
// accumulated in registers across the 7 same-batch tiles (atomics / 7).
// LDS 65KB -> 2 blocks/CU; __launch_bounds__(256,2) keeps VGPRs unconstrained.
// ---------------------------------------------------------------------------
__global__ __launch_bounds__(256, 2) void fused_mlp_bf16(
    const float* __restrict__ gnn, const short* __restrict__ B0p,
    const float* __restrict__ b1, const float* __restrict__ W2,
    const float* __restrict__ b2,
    float* __restrict__ Dreg, float* __restrict__ Wreg, float* __restrict__ emb)
{
    __shared__ __align__(16) char ldsbuf[2][32768];   // ping-pong stage/Abf
    __shared__ float red0[4][32];
    __shared__ float red1[4][32];

    const int t = threadIdx.x;
    const int w = t >> 6, l = t & 63;
    const int batch = blockIdx.x >> 1;
    const int tile0 = (blockIdx.x & 1) * TPB;         // 0 or 7
    const long bbase = (long)batch * NN;

    // convert/staging decode (constant across phases)
    const int kk_s = l >> 3;          // k-step of this lane's chunk
    const int fk_s = (l >> 1) & 3;    // frag lane group
    const int jh_s = l & 1;           // elem half
    const int frow = l & 15;
    const int fk   = l >> 4;

    // invariant epilogue weights
    float w20[4], w21[4], b1v[4];
    #pragma unroll
    for (int n = 0; n < 4; n++) {
        int cc = (((w << 2) + n) << 4) + frow;
        b1v[n] = b1[cc];
        w20[n] = W2[2 * cc];
        w21[n] = W2[2 * cc + 1];
    }
    const float b20 = b2[0], b21 = b2[1];

    // DMA of one tile into buffer `buf` (8 x 1KB rows per wave, linear lanes)
    auto DMA = [&](int p, int buf) {
        const long row0 = bbase + (long)(tile0 + p) * TROWS;
        float* st = (float*)ldsbuf[buf];
        #pragma unroll
        for (int i = 0; i < 8; i++) {
            int r = (w << 3) + i;
            long ar = row0 + r;
            if (ar >= (long)TOT_ROWS) ar = TOT_ROWS - 1;   // global-end clamp
            const float* gsrc = gnn + ar * HNF + (l << 2);
            __builtin_amdgcn_global_load_lds(
                (const __attribute__((address_space(1))) unsigned*)gsrc,
                (__attribute__((address_space(3))) unsigned*)(st + (r << 8)),
                16, 0, 0);
        }
    };

    DMA(0, 0);
    DMA(1, 1);

    float embp[4] = {0.f, 0.f, 0.f, 0.f};

    #pragma unroll 1
    for (int p = 0; p < TPB; ++p) {
        const int cur = p & 1;
        float* stage = (float*)ldsbuf[cur];
        short* Abf   = (short*)ldsbuf[cur];
        const int tile = tile0 + p;
        const long row0 = bbase + (long)tile * TROWS;
        const int vr = (tile == TILES_PB - 1) ? (NN - (TILES_PB - 1) * TROWS) : TROWS;

        // wait: this tile's DMA done (next tile's 8 may stay in flight)
        if (p < TPB - 1) asm volatile("s_waitcnt vmcnt(8)" ::: "memory");
        else             asm volatile("s_waitcnt vmcnt(0)" ::: "memory");

        // ---- convert own rows (lane-linear reads, conflict-free) ----
        uint2 pv[8];
        #pragma unroll
        for (int i = 0; i < 8; i++) {
            float4 f = *(const float4*)(stage + (((w << 3) + i) << 8) + (l << 2));
            pv[i].x = pk_bf16(f.x, f.y);
            pv[i].y = pk_bf16(f.z, f.w);
        }
        __syncthreads();   // all stage reads done before Abf overlay
        #pragma unroll
        for (int i = 0; i < 8; i++) {
            int r = (w << 3) + i;
            int di = (((kk_s << 1) + (r >> 4)) << 6) | (fk_s << 4) | (r & 15);
            *(uint2*)((char*)Abf + (((size_t)(di ^ kk_s)) << 4) + (jh_s << 3)) = pv[i];
        }
        __syncthreads();   // Abf visible to all waves

        // ---- MFMA: 8 k-steps x (2m x 4n) per wave ----
        float4v acc[2][4];
        #pragma unroll
        for (int m = 0; m < 2; m++)
            #pragma unroll
            for (int n = 0; n < 4; n++)
                acc[m][n] = (float4v){0.f, 0.f, 0.f, 0.f};

        #pragma unroll 2
        for (int kk = 0; kk < 8; ++kk) {
            short8 bf[4], af[2];
            #pragma unroll
            for (int n = 0; n < 4; n++) {
                int nf = (w << 2) + n;
                size_t off = (size_t)((((kk << 4) + nf) << 6) | l) << 3;
                bf[n] = *(const short8*)(B0p + off);
            }
            #pragma unroll
            for (int m = 0; m < 2; m++) {
                int di = ((((kk << 1) + m) << 6) | l) ^ kk;   // undo write swizzle
                af[m] = *(const short8*)(Abf + (size_t)di * 8);
            }
            #pragma unroll
            for (int m = 0; m < 2; m++)
                #pragma unroll
                for (int n = 0; n < 4; n++)
                    acc[m][n] = __builtin_amdgcn_mfma_f32_16x16x32_bf16(af[m], bf[n], acc[m][n], 0, 0, 0);
        }

        // ---- epilogue: bias+relu, e2 row-dots, emb register accumulation ----
        float ps0[2][4], ps1[2][4];
        #pragma unroll
        for (int m = 0; m < 2; m++)
            #pragma unroll
            for (int j = 0; j < 4; j++) { ps0[m][j] = 0.f; ps1[m][j] = 0.f; }

        #pragma unroll
        for (int m = 0; m < 2; m++)
            #pragma unroll
            for (int n = 0; n < 4; n++)
                #pragma unroll
                for (int j = 0; j < 4; j++) {
                    float h = fmaxf(acc[m][n][j] + b1v[n], 0.f);
                    ps0[m][j] += h * w20[n];
                    ps1[m][j] += h * w21[n];
                    int row = (m << 4) + (fk << 2) + j;
                    if (row < vr) embp[n] += h;      // exclude pad rows
                }

        #pragma unroll
        for (int off = 1; off < 16; off <<= 1)
            #pragma unroll
            for (int m = 0; m < 2; m++)
                #pragma unroll
                for (int j = 0; j < 4; j++) {
                    ps0[m][j] += __shfl_xor(ps0[m][j], off);
                    ps1[m][j] += __shfl_xor(ps1[m][j], off);
                }
        if (frow == 0) {
            #pragma unroll
            for (int m = 0; m < 2; m++)
                #pragma unroll
                for (int j = 0; j < 4; j++) {
                    int row = (m << 4) + (fk << 2) + j;
                    red0[w][row] = ps0[m][j];
                    red1[w][row] = ps1[m][j];
                }
        }
        __syncthreads();   // red ready; also: all Abf reads of this tile done
        if (t < vr) {
            float v0 = b20 + red0[0][t] + red0[1][t] + red0[2][t] + red0[3][t];
            float v1 = b21 + red1[0][t] + red1[1][t] + red1[2][t] + red1[3][t];
            Dreg[row0 + t] = v0;    // raw e2 ch0 (symmetrized in recon)
            Wreg[row0 + t] = v1;
        }

        // prefetch tile p+2 into the buffer just freed (DMA queue, no VGPRs)
        if (p + 2 < TPB) DMA(p + 2, cur);
    }

    // ---- emb: one reduce + one atomic per thread for the whole block ----
    #pragma unroll
    for (int n = 0; n < 4; n++) {
        embp[n] += __shfl_xor(embp[n], 16);
        embp[n] += __shfl_xor(embp[n], 32);
    }
    if (l < 16) {
        #pragma unroll
        for (int n = 0; n < 4; n++)
            atomicAdd(emb + (size_t)batch * 256 + (((w << 2) + n) << 4) + l, embp[n]);
    }
}

// ---------------------------------------------------------------------------
// Kernel 2 (unchanged from R11): sym+softplus + register MDS recon, split-q
// across lane halves, LDS same-address broadcasts, readlane-free.
// ---------------------------------------------------------------------------
__global__ __launch_bounds__(64) void symrecon_kernel(
    float* __restrict__ Dreg, float* __restrict__ Wreg,
    const float* __restrict__ un, const float* __restrict__ xn,
    float* __restrict__ Xo)
{
    const int b = blockIdx.x, l = threadIdx.x;
    __shared__ float R0[NN], R1[NN];
    __shared__ float Rs[22], Us[22], Xs[3][22];

    float* Db = Dreg + (size_t)b * NN;
    float* Wb = Wreg + (size_t)b * NN;
    for (int idx = l; idx < NN; idx += 64) { R0[idx] = Db[idx]; R1[idx] = Wb[idx]; }
    if (l == 0) { Rs[21] = 0.f; Us[21] = 0.f; Xs[0][21] = 0.f; Xs[1][21] = 0.f; Xs[2][21] = 0.f; }
    __syncthreads();

    const int half = l >> 5;          // 0: q 0..10, 1: q 11..20 (+pad 21)
    const int li   = l & 31;          // point index
    const bool act = li < NMAX;
    const int li0  = act ? li : 0;
    const int q0   = half * 11;

    // ---- symmetrize + softplus, half-row per lane ----
    float Drow[11], Wrow[11], WD[11];
    float rsh = 0.f;
    #pragma unroll
    for (int j = 0; j < 11; j++) {
        int q = q0 + j;
        bool v = act && (q < NMAX);
        int qc = v ? q : 0;
        float rd = R0[li0 * NMAX + qc] + R0[qc * NMAX + li0];
        float rw = R1[li0 * NMAX + qc] + R1[qc * NMAX + li0];
        float d  = (v && q != li) ? softplus_fast(rd) : 0.f;
        float wv = v ? softplus_fast(rw) : 0.f;
        Drow[j] = d; Wrow[j] = wv; WD[j] = wv * d;
        rsh += d;
    }
    if (act) {
        #pragma unroll
        for (int j = 0; j < 11; j++) {
            int q = q0 + j;
            if (q < NMAX) {
                Db[li * NMAX + q] = Drow[j];
                Wb[li * NMAX + q] = Wrow[j];
            }
        }
    }

    // ---- double-centering ----
    float rsf = rsh + __shfl_xor(rsh, 32);   // full row sum for point li
    float tot = rsh;
    #pragma unroll
    for (int m = 1; m < 64; m <<= 1) tot += __shfl_xor(tot, m);
    const float mean = tot * (1.f / (float)NN);
    const float rsn  = rsf * (1.f / (float)NMAX);
    if (act && half == 0) Rs[li] = rsn;      // broadcast table (wave-ordered)
    float Arow[11];
    #pragma unroll
    for (int j = 0; j < 11; j++) {
        int q = q0 + j;
        bool v = act && (q < NMAX);
        float rsq = Rs[q];                   // LDS broadcast (pad q=21 -> 0)
        Arow[j] = v ? -0.5f * (Drow[j] - rsn - rsq + mean) : 0.f;
    }

    // ---- deflated power iteration: k=3 eigvecs, 10 steps each ----
    float xc[3];
    #pragma unroll
    for (int e = 0; e < 3; e++) {
        float u = act ? un[(size_t)b * 63 + e * NMAX + li] : 0.f;
        for (int s = 0; s < 10; s++) {
            float n2 = (act && half == 0) ? u * u : 0.f;
            #pragma unroll
            for (int m = 1; m < 64; m <<= 1) n2 += __shfl_xor(n2, m);
            u *= fminf(__builtin_amdgcn_rsqf(n2), 1000.f);
            if (act && half == 0) Us[li] = u;
            float a = 0.f;
            #pragma unroll
            for (int j = 0; j < 11; j++) a = fmaf(Arow[j], Us[q0 + j], a);
            a += __shfl_xor(a, 32);
            u = act ? a : 0.f;
        }
        float e2 = (act && half == 0) ? u * u : 0.f;
        #pragma unroll
        for (int m = 1; m < 64; m <<= 1) e2 += __shfl_xor(e2, m);
        u *= sqrtf(__builtin_amdgcn_rsqf(e2 + 0.01f));   // (e2+.01)^-0.25
        xc[e] = u;
        if (act && half == 0) Us[li] = u;
        #pragma unroll
        for (int j = 0; j < 11; j++) Arow[j] = fmaf(-u, Us[q0 + j], Arow[j]);
    }
    float x = xc[0], y = xc[1], z = xc[2];
    if (act) {
        x += xn[(size_t)b * 63 + li * 3 + 0];
        y += xn[(size_t)b * 63 + li * 3 + 1];
        z += xn[(size_t)b * 63 + li * 3 + 2];
    }
    if (act && half == 0) { Xs[0][li] = x; Xs[1][li] = y; Xs[2][li] = z; }

    // ---- 100 clipped GD steps: half-q per lane, LDS X broadcasts ----
    for (int tstep = 0; tstep < 100; tstep++) {
        float gx = 0.f, gy = 0.f, gz = 0.f;
        #pragma unroll
        for (int j = 0; j < 11; j++) {
            int q = q0 + j;
            float dx = x - Xs[0][q];
            float dy = y - Xs[1][q];
            float dz = z - Xs[2][q];
            float s  = fmaf(dx, dx, fmaf(dy, dy, fmaf(dz, dz, 0.01f)));
            float cm = fmaf(-Wrow[j], s, WD[j]);   // W*(D - s), pad -> 0
            gx = fmaf(cm, dx, gx);
            gy = fmaf(cm, dy, gy);
            gz = fmaf(cm, dz, gz);
        }
        gx += __shfl_xor(gx, 32);
        gy += __shfl_xor(gy, 32);
        gz += __shfl_xor(gz, 32);
        float d0 = 0.8f * gx, d1 = 0.8f * gy, d2 = 0.8f * gz;
        float ss = fmaf(d0, d0, fmaf(d1, d1, fmaf(d2, d2, 1e-3f)));
        float inv_sp = __builtin_amdgcn_rsqf(ss);
        float speed  = ss * inv_sp;
        float alpha  = fmaf(-0.049f, (float)tstep, 5.0f);
        float th     = tanh_fast(speed * __builtin_amdgcn_rcpf(alpha));
        float scale  = alpha * th * inv_sp;
        x = fmaf(d0, scale, x);
        y = fmaf(d1, scale, y);
        z = fmaf(d2, scale, z);
        if (act && half == 0) { Xs[0][li] = x; Xs[1][li] = y; Xs[2][li] = z; }
    }
    if (act && half == 0) {
        Xo[(size_t)b * 63 + li * 3 + 0] = x;
        Xo[(size_t)b * 63 + li * 3 + 1] = y;
        Xo[(size_t)b * 63 + li * 3 + 2] = z;
    }
}

// ---------------------------------------------------------------------------
extern "C" void kernel_launch(void* const* d_in, const int* in_sizes, int n_in,
                              void* d_out, int out_size, void* d_ws, size_t ws_size,
                              hipStream_t stream) {
    const float* gnn = (const float*)d_in[0];
    const float* W1  = (const float*)d_in[1];
    const float* b1  = (const float*)d_in[2];
    const float* W2  = (const float*)d_in[3];
    const float* b2  = (const float*)d_in[4];
    const float* un  = (const float*)d_in[5];
    const float* xn  = (const float*)d_in[6];

    float* out  = (float*)d_out;
    float* Dreg = out;                                  // [1024*441]
    float* Wreg = out + (size_t)TOT_ROWS;               // [1024*441]
    float* emb  = out + (size_t)2 * TOT_ROWS;           // [1024*256]
    float* Xo   = out + (size_t)2 * TOT_ROWS + B_SZ*256;// [1024*63]

    short* B0p = (short*)d_ws;                          // 65536 bf16 (128KB)

    pack_w1<<<dim3(256), dim3(256), 0, stream>>>(W1, B0p, emb);

    fused_mlp_bf16<<<dim3(B_SZ * 2), dim3(256), 0, stream>>>(
        gnn, B0p, b1, W2, b2, Dreg, Wreg, emb);

    symrecon_kernel<<<dim3(B_SZ), dim3(64), 0, stream>>>(Dreg, Wreg, un, xn, Xo);
}

// Round 15
// 242.902 us; speedup vs baseline: 1.0792x; 1.0792x over previous
//
#include <hip/hip_runtime.h>
#include <hip/hip_bf16.h>
#include <math.h>

#define B_SZ 1024
#define NMAX 21
#define NN 441            // 21*21
#define HNF 256
#define TOT_ROWS (B_SZ * NN)   // 451584
#define TILES_PB 14            // 14 tiles of 32 rows per batch (448 >= 441)
#define TROWS 32

typedef short short8 __attribute__((ext_vector_type(8)));
typedef float float4v __attribute__((ext_vector_type(4)));

__device__ __forceinline__ unsigned short f2bf(float x) {
    union { float f; unsigned int u; } v; v.f = x;
    unsigned int r = v.u + 0x7FFFu + ((v.u >> 16) & 1u);   // RNE
    return (unsigned short)(r >> 16);
}

// hardware packed fp32->bf16 (v_cvt_pk_bf16_f32), RNE
__device__ __forceinline__ unsigned pk_bf16(float lo, float hi) {
    __hip_bfloat162 h = __float22bfloat162_rn(float2{lo, hi});
    return *reinterpret_cast<unsigned*>(&h);
}

// fast softplus: max(x,0) + ln2*log2(1 + exp2(-|x|*log2e)), raw v_exp/v_log
__device__ __forceinline__ float softplus_fast(float x) {
    float e = __builtin_amdgcn_exp2f(-fabsf(x) * 1.44269504088896f);
    float lg = __builtin_amdgcn_logf(1.f + e);
    return fmaxf(x, 0.f) + 0.69314718055995f * lg;
}

// fast tanh for x>=0: 1 - 2/(exp2(x*2log2e)+1). v_exp/v_rcp approx (~1e-7).
__device__ __forceinline__ float tanh_fast(float x) {
    float e = __builtin_amdgcn_exp2f(x * 2.8853900817779268f);
    float q = __builtin_amdgcn_rcpf(e + 1.f);
    return fmaf(-2.f, q, 1.f);
}

// ---------------------------------------------------------------------------
// Pack W1 into MFMA B-fragment order as bf16 (+ zero emb, folded in).
// ---------------------------------------------------------------------------
__global__ __launch_bounds__(256) void pack_w1(const float* __restrict__ W1,
                                               short* __restrict__ B0p,
                                               float* __restrict__ emb)
{
    int id = blockIdx.x * 256 + threadIdx.x;   // 0..65535
    int j = id & 7, l = (id >> 3) & 63, f = (id >> 9) & 15, s = id >> 13;
    int k = s * 32 + ((l >> 4) << 3) + j;
    int c = (f << 4) + (l & 15);
    B0p[id] = (short)f2bf(W1[k * HNF + c]);
    #pragma unroll
    for (int e = 0; e < 4; e++)
        emb[(size_t)e * 65536 + id] = 0.f;     // 4*65536 = 1024*256
}

// ---------------------------------------------------------------------------
// Kernel 1 (R15 = R13 + 5 blocks/CU): 32-row tiles, 256-thread blocks.
// LDS request is EXACTLY 32768B: red0/red1 overlay stage bytes 16384..17407
// (stage rows 16-17, dead after the convert phase's reads complete at
// barrier 1; red is only written post-MFMA after barrier 2). 5 x 32KB =
// 160KB -> 5 resident blocks/CU (20 waves), +25% independent DMA streams.
// __launch_bounds__(256,5) caps VGPR at ~102 (kernel measured ~64, safe).
// Everything else identical to R13 (best measured: 245.7us).
// ---------------------------------------------------------------------------
__global__ __launch_bounds__(256, 5) void fused_mlp_bf16(
    const float* __restrict__ gnn, const short* __restrict__ B0p,
    const float* __restrict__ b1, const float* __restrict__ W2,
    const float* __restrict__ b2,
    float* __restrict__ Dreg, float* __restrict__ Wreg, float* __restrict__ emb)
{
    __shared__ __align__(16) char ldsbuf[32768];
    float* stage = (float*)ldsbuf;     // [32][256] fp32, linear
    short* Abf   = (short*)ldsbuf;     // 16KB frag-linear bf16 overlay
    float (*red0)[32] = (float(*)[32])(ldsbuf + 16384);        // overlay
    float (*red1)[32] = (float(*)[32])(ldsbuf + 16384 + 512);  // rows 16-17

    const int t = threadIdx.x;
    const int w = t >> 6, l = t & 63;
    const int batch = blockIdx.x / TILES_PB;
    const int tile  = blockIdx.x % TILES_PB;
    const long row0 = (long)batch * NN + (long)tile * TROWS;
    const int vr = (tile == TILES_PB - 1) ? (NN - (TILES_PB - 1) * TROWS) : TROWS; // 25 or 32

    // ---- DMA: wave w stages rows w*8..w*8+7, linear lane addresses ----
    #pragma unroll
    for (int i = 0; i < 8; i++) {
        int r = (w << 3) + i;                          // 0..31
        long ar = row0 + r;
        if (ar >= (long)TOT_ROWS) ar = TOT_ROWS - 1;   // global-end clamp
        const float* gsrc = gnn + ar * HNF + (l << 2); // lane l -> 16B chunk l
        __builtin_amdgcn_global_load_lds(
            (const __attribute__((address_space(1))) unsigned*)gsrc,
            (__attribute__((address_space(3))) unsigned*)(stage + (r << 8)),
            16, 0, 0);
    }

    // ---- convert ladder: own rows, lane-linear reads ----
    uint2 pv[8];
    asm volatile("s_waitcnt vmcnt(4)" ::: "memory");   // rows w*8..w*8+3 landed
    #pragma unroll
    for (int i = 0; i < 4; i++) {
        float4 f = *(const float4*)(stage + (((w << 3) + i) << 8) + (l << 2));
        pv[i].x = pk_bf16(f.x, f.y);
        pv[i].y = pk_bf16(f.z, f.w);
    }
    asm volatile("s_waitcnt vmcnt(0)" ::: "memory");   // rows w*8+4..w*8+7
    #pragma unroll
    for (int i = 4; i < 8; i++) {
        float4 f = *(const float4*)(stage + (((w << 3) + i) << 8) + (l << 2));
        pv[i].x = pk_bf16(f.x, f.y);
        pv[i].y = pk_bf16(f.z, f.w);
    }
    __syncthreads();   // all waves' stage reads complete before Abf overlay

    const int kk_s = l >> 3;          // k-step of this lane's chunk
    const int fk_s = (l >> 1) & 3;    // frag lane group
    const int jh_s = l & 1;           // elem half
    #pragma unroll
    for (int i = 0; i < 8; i++) {
        int r = (w << 3) + i;
        int di = (((kk_s << 1) + (r >> 4)) << 6) | (fk_s << 4) | (r & 15);
        *(uint2*)((char*)Abf + (((size_t)(di ^ kk_s)) << 4) + (jh_s << 3)) = pv[i];
    }
    __syncthreads();   // Abf visible to all waves

    // fragment decode for compute
    const int frow = l & 15;
    const int fk   = l >> 4;

    // ---- MFMA loop: 8 k-steps x (2m x 4n) per wave ----
    float4v acc[2][4];
    #pragma unroll
    for (int m = 0; m < 2; m++)
        #pragma unroll
        for (int n = 0; n < 4; n++)
            acc[m][n] = (float4v){0.f, 0.f, 0.f, 0.f};

    #pragma unroll 2
    for (int kk = 0; kk < 8; ++kk) {
        short8 bf[4], af[2];
        #pragma unroll
        for (int n = 0; n < 4; n++) {
            int nf = (w << 2) + n;
            size_t off = (size_t)((((kk << 4) + nf) << 6) | l) << 3;
            bf[n] = *(const short8*)(B0p + off);
        }
        #pragma unroll
        for (int m = 0; m < 2; m++) {
            int di = ((((kk << 1) + m) << 6) | l) ^ kk;   // undo write swizzle
            af[m] = *(const short8*)(Abf + (size_t)di * 8);
        }
        #pragma unroll
        for (int m = 0; m < 2; m++)
            #pragma unroll
            for (int n = 0; n < 4; n++)
                acc[m][n] = __builtin_amdgcn_mfma_f32_16x16x32_bf16(af[m], bf[n], acc[m][n], 0, 0, 0);
    }

    // ---- epilogue: bias+relu, e2 row-dots, emb partials ----
    // C frag: col = (4w+n)*16 + (l&15), row = m*16 + (l>>4)*4 + j
    float w20[4], w21[4], b1v[4];
    #pragma unroll
    for (int n = 0; n < 4; n++) {
        int cc = (((w << 2) + n) << 4) + frow;
        b1v[n] = b1[cc];
        w20[n] = W2[2 * cc];
        w21[n] = W2[2 * cc + 1];
    }
    float ps0[2][4], ps1[2][4], embp[4] = {0.f, 0.f, 0.f, 0.f};
    #pragma unroll
    for (int m = 0; m < 2; m++)
        #pragma unroll
        for (int j = 0; j < 4; j++) { ps0[m][j] = 0.f; ps1[m][j] = 0.f; }

    #pragma unroll
    for (int m = 0; m < 2; m++)
        #pragma unroll
        for (int n = 0; n < 4; n++)
            #pragma unroll
            for (int j = 0; j < 4; j++) {
                float h = fmaxf(acc[m][n][j] + b1v[n], 0.f);
                ps0[m][j] += h * w20[n];
                ps1[m][j] += h * w21[n];
                int row = (m << 4) + (fk << 2) + j;
                if (row < vr) embp[n] += h;      // exclude pad rows
            }

    #pragma unroll
    for (int off = 1; off < 16; off <<= 1)
        #pragma unroll
        for (int m = 0; m < 2; m++)
            #pragma unroll
            for (int j = 0; j < 4; j++) {
                ps0[m][j] += __shfl_xor(ps0[m][j], off);
                ps1[m][j] += __shfl_xor(ps1[m][j], off);
            }
    if (frow == 0) {
        #pragma unroll
        for (int m = 0; m < 2; m++)
            #pragma unroll
            for (int j = 0; j < 4; j++) {
                int row = (m << 4) + (fk << 2) + j;
                red0[w][row] = ps0[m][j];
                red1[w][row] = ps1[m][j];
            }
    }

    #pragma unroll
    for (int n = 0; n < 4; n++) {
        embp[n] += __shfl_xor(embp[n], 16);
        embp[n] += __shfl_xor(embp[n], 32);
    }
    if (l < 16) {
        #pragma unroll
        for (int n = 0; n < 4; n++)
            atomicAdd(emb + (size_t)batch * 256 + (((w << 2) + n) << 4) + l, embp[n]);
    }

    __syncthreads();
    if (t < vr) {
        float v0 = b2[0] + red0[0][t] + red0[1][t] + red0[2][t] + red0[3][t];
        float v1 = b2[1] + red1[0][t] + red1[1][t] + red1[2][t] + red1[3][t];
        Dreg[row0 + t] = v0;    // raw e2 ch0 (symmetrized in recon)
        Wreg[row0 + t] = v1;
    }
}

// ---------------------------------------------------------------------------
// Kernel 2 (unchanged from R11): sym+softplus + register MDS recon, split-q
// across lane halves, LDS same-address broadcasts, readlane-free.
// ---------------------------------------------------------------------------
__global__ __launch_bounds__(64) void symrecon_kernel(
    float* __restrict__ Dreg, float* __restrict__ Wreg,
    const float* __restrict__ un, const float* __restrict__ xn,
    float* __restrict__ Xo)
{
    const int b = blockIdx.x, l = threadIdx.x;
    __shared__ float R0[NN], R1[NN];
    __shared__ float Rs[22], Us[22], Xs[3][22];

    float* Db = Dreg + (size_t)b * NN;
    float* Wb = Wreg + (size_t)b * NN;
    for (int idx = l; idx < NN; idx += 64) { R0[idx] = Db[idx]; R1[idx] = Wb[idx]; }
    if (l == 0) { Rs[21] = 0.f; Us[21] = 0.f; Xs[0][21] = 0.f; Xs[1][21] = 0.f; Xs[2][21] = 0.f; }
    __syncthreads();

    const int half = l >> 5;          // 0: q 0..10, 1: q 11..20 (+pad 21)
    const int li   = l & 31;          // point index
    const bool act = li < NMAX;
    const int li0  = act ? li : 0;
    const int q0   = half * 11;

    // ---- symmetrize + softplus, half-row per lane ----
    float Drow[11], Wrow[11], WD[11];
    float rsh = 0.f;
    #pragma unroll
    for (int j = 0; j < 11; j++) {
        int q = q0 + j;
        bool v = act && (q < NMAX);
        int qc = v ? q : 0;
        float rd = R0[li0 * NMAX + qc] + R0[qc * NMAX + li0];
        float rw = R1[li0 * NMAX + qc] + R1[qc * NMAX + li0];
        float d  = (v && q != li) ? softplus_fast(rd) : 0.f;
        float wv = v ? softplus_fast(rw) : 0.f;
        Drow[j] = d; Wrow[j] = wv; WD[j] = wv * d;
        rsh += d;
    }
    if (act) {
        #pragma unroll
        for (int j = 0; j < 11; j++) {
            int q = q0 + j;
            if (q < NMAX) {
                Db[li * NMAX + q] = Drow[j];
                Wb[li * NMAX + q] = Wrow[j];
            }
        }
    }

    // ---- double-centering ----
    float rsf = rsh + __shfl_xor(rsh, 32);   // full row sum for point li
    float tot = rsh;
    #pragma unroll
    for (int m = 1; m < 64; m <<= 1) tot += __shfl_xor(tot, m);
    const float mean = tot * (1.f / (float)NN);
    const float rsn  = rsf * (1.f / (float)NMAX);
    if (act && half == 0) Rs[li] = rsn;      // broadcast table (wave-ordered)
    float Arow[11];
    #pragma unroll
    for (int j = 0; j < 11; j++) {
        int q = q0 + j;
        bool v = act && (q < NMAX);
        float rsq = Rs[q];                   // LDS broadcast (pad q=21 -> 0)
        Arow[j] = v ? -0.5f * (Drow[j] - rsn - rsq + mean) : 0.f;
    }

    // ---- deflated power iteration: k=3 eigvecs, 10 steps each ----
    float xc[3];
    #pragma unroll
    for (int e = 0; e < 3; e++) {
        float u = act ? un[(size_t)b * 63 + e * NMAX + li] : 0.f;
        for (int s = 0; s < 10; s++) {
            float n2 = (act && half == 0) ? u * u : 0.f;
            #pragma unroll
            for (int m = 1; m < 64; m <<= 1) n2 += __shfl_xor(n2, m);
            u *= fminf(__builtin_amdgcn_rsqf(n2), 1000.f);
            if (act && half == 0) Us[li] = u;
            float a = 0.f;
            #pragma unroll
            for (int j = 0; j < 11; j++) a = fmaf(Arow[j], Us[q0 + j], a);
            a += __shfl_xor(a, 32);
            u = act ? a : 0.f;
        }
        float e2 = (act && half == 0) ? u * u : 0.f;
        #pragma unroll
        for (int m = 1; m < 64; m <<= 1) e2 += __shfl_xor(e2, m);
        u *= sqrtf(__builtin_amdgcn_rsqf(e2 + 0.01f));   // (e2+.01)^-0.25
        xc[e] = u;
        if (act && half == 0) Us[li] = u;
        #pragma unroll
        for (int j = 0; j < 11; j++) Arow[j] = fmaf(-u, Us[q0 + j], Arow[j]);
    }
    float x = xc[0], y = xc[1], z = xc[2];
    if (act) {
        x += xn[(size_t)b * 63 + li * 3 + 0];
        y += xn[(size_t)b * 63 + li * 3 + 1];
        z += xn[(size_t)b * 63 + li * 3 + 2];
    }
    if (act && half == 0) { Xs[0][li] = x; Xs[1][li] = y; Xs[2][li] = z; }

    // ---- 100 clipped GD steps: half-q per lane, LDS X broadcasts ----
    for (int tstep = 0; tstep < 100; tstep++) {
        float gx = 0.f, gy = 0.f, gz = 0.f;
        #pragma unroll
        for (int j = 0; j < 11; j++) {
            int q = q0 + j;
            float dx = x - Xs[0][q];
            float dy = y - Xs[1][q];
            float dz = z - Xs[2][q];
            float s  = fmaf(dx, dx, fmaf(dy, dy, fmaf(dz, dz, 0.01f)));
            float cm = fmaf(-Wrow[j], s, WD[j]);   // W*(D - s), pad -> 0
            gx = fmaf(cm, dx, gx);
            gy = fmaf(cm, dy, gy);
            gz = fmaf(cm, dz, gz);
        }
        gx += __shfl_xor(gx, 32);
        gy += __shfl_xor(gy, 32);
        gz += __shfl_xor(gz, 32);
        float d0 = 0.8f * gx, d1 = 0.8f * gy, d2 = 0.8f * gz;
        float ss = fmaf(d0, d0, fmaf(d1, d1, fmaf(d2, d2, 1e-3f)));
        float inv_sp = __builtin_amdgcn_rsqf(ss);
        float speed  = ss * inv_sp;
        float alpha  = fmaf(-0.049f, (float)tstep, 5.0f);
        float th     = tanh_fast(speed * __builtin_amdgcn_rcpf(alpha));
        float scale  = alpha * th * inv_sp;
        x = fmaf(d0, scale, x);
        y = fmaf(d1, scale, y);
        z = fmaf(d2, scale, z);
        if (act && half == 0) { Xs[0][li] = x; Xs[1][li] = y; Xs[2][li] = z; }
    }
    if (act && half == 0) {
        Xo[(size_t)b * 63 + li * 3 + 0] = x;
        Xo[(size_t)b * 63 + li * 3 + 1] = y;
        Xo[(size_t)b * 63 + li * 3 + 2] = z;
    }
}

// ---------------------------------------------------------------------------
extern "C" void kernel_launch(void* const* d_in, const int* in_sizes, int n_in,
                              void* d_out, int out_size, void* d_ws, size_t ws_size,
                              hipStream_t stream) {
    const float* gnn = (const float*)d_in[0];
    const float* W1  = (const float*)d_in[1];
    const float* b1  = (const float*)d_in[2];
    const float* W2  = (const float*)d_in[3];
    const float* b2  = (const float*)d_in[4];
    const float* un  = (const float*)d_in[5];
    const float* xn  = (const float*)d_in[6];

    float* out  = (float*)d_out;
    float* Dreg = out;                                  // [1024*441]
    float* Wreg = out + (size_t)TOT_ROWS;               // [1024*441]
    float* emb  = out + (size_t)2 * TOT_ROWS;           // [1024*256]
    float* Xo   = out + (size_t)2 * TOT_ROWS + B_SZ*256;// [1024*63]

    short* B0p = (short*)d_ws;                          // 65536 bf16 (128KB)

    pack_w1<<<dim3(256), dim3(256), 0, stream>>>(W1, B0p, emb);

    fused_mlp_bf16<<<dim3(B_SZ * TILES_PB), dim3(256), 0, stream>>>(
        gnn, B0p, b1, W2, b2, Dreg, Wreg, emb);

    symrecon_kernel<<<dim3(B_SZ), dim3(64), 0, stream>>>(Dreg, Wreg, un, xn, Xo);
}